// Round 2
// baseline (646.588 us; speedup 1.0000x reference)
//
#include <hip/hip_runtime.h>

#define N_NODES 100000
#define N_EDGES 1600000
#define IN_DIM 256
#define HEADS 4
#define OUT_DIM 32
#define NHD 128          // HEADS*OUT_DIM
#define LEAKY 0.2f

// ---------------------------------------------------------------- init ----
__global__ void init_kernel(int* __restrict__ deg, int* __restrict__ cursor) {
    int i = blockIdx.x * blockDim.x + threadIdx.x;
    if (i < N_NODES) { deg[i] = 0; cursor[i] = 0; }
}

// ---------------------------------------------------------------- gemm ----
// ft[N,128] = feature[N,256] @ W[256,128]; fused a1/a2 = sum(ft*attn_{l,r}, -1) per head.
// Tile: 64 nodes x 128 cols, K-tiles of 64. Per thread: 4 nodes x 8 cols.
__launch_bounds__(256, 2)
__global__ void gemm_kernel(const float* __restrict__ feature,
                            const float* __restrict__ W,
                            const float* __restrict__ attn_l,
                            const float* __restrict__ attn_r,
                            float* __restrict__ ft,
                            float* __restrict__ a1,
                            float* __restrict__ a2) {
    // sA transposed [k][node], stride 65 -> scalar reads, max 2-way conflict (free)
    __shared__ float sA[64][65];    // 16.6 KB
    __shared__ float sW[64][132];   // 33.8 KB
    const int t  = threadIdx.x;
    const int tx = t & 15;          // col group: cols tx*8 .. tx*8+7
    const int ty = t >> 4;          // node group: nodes ty*4 .. ty*4+3
    const int nb = blockIdx.x * 64;

    float acc[4][8];
#pragma unroll
    for (int i = 0; i < 4; ++i)
#pragma unroll
        for (int j = 0; j < 8; ++j) acc[i][j] = 0.f;

    for (int kt = 0; kt < 4; ++kt) {
        __syncthreads();
        // load feature tile 64 nodes x 64 k, transposed
#pragma unroll
        for (int p = 0; p < 4; ++p) {
            int idx  = t + p * 256;       // 0..1023 float4 slots
            int row  = idx >> 4;          // node 0..63
            int c4   = idx & 15;          // float4 index within 64 k
            int node = nb + row;
            float4 v = make_float4(0.f, 0.f, 0.f, 0.f);
            if (node < N_NODES)
                v = *(const float4*)&feature[(size_t)node * IN_DIM + kt * 64 + c4 * 4];
            sA[c4 * 4 + 0][row] = v.x;
            sA[c4 * 4 + 1][row] = v.y;
            sA[c4 * 4 + 2][row] = v.z;
            sA[c4 * 4 + 3][row] = v.w;
        }
        // load W tile 64 k x 128 cols
#pragma unroll
        for (int p = 0; p < 8; ++p) {
            int idx = t + p * 256;        // 0..2047 float4 slots
            int row = idx >> 5;           // k 0..63
            int c4  = idx & 31;           // float4 col
            float4 v = *(const float4*)&W[(size_t)(kt * 64 + row) * NHD + c4 * 4];
            *(float4*)&sW[row][c4 * 4] = v;
        }
        __syncthreads();

#pragma unroll 4
        for (int k = 0; k < 64; ++k) {
            float a[4];
#pragma unroll
            for (int i = 0; i < 4; ++i) a[i] = sA[k][ty * 4 + i];
            float4 b0 = *(const float4*)&sW[k][tx * 8];
            float4 b1 = *(const float4*)&sW[k][tx * 8 + 4];
            float b[8] = {b0.x, b0.y, b0.z, b0.w, b1.x, b1.y, b1.z, b1.w};
#pragma unroll
            for (int i = 0; i < 4; ++i)
#pragma unroll
                for (int j = 0; j < 8; ++j)
                    acc[i][j] = fmaf(a[i], b[j], acc[i][j]);
        }
    }

    // attn vectors for my 8 cols (all within one head: head = tx>>2)
    float al[8], ar[8];
#pragma unroll
    for (int j = 0; j < 8; ++j) {
        al[j] = attn_l[tx * 8 + j];
        ar[j] = attn_r[tx * 8 + j];
    }

#pragma unroll
    for (int i = 0; i < 4; ++i) {
        int node = nb + ty * 4 + i;
        if (node < N_NODES) {
            float4 s0 = make_float4(acc[i][0], acc[i][1], acc[i][2], acc[i][3]);
            float4 s1 = make_float4(acc[i][4], acc[i][5], acc[i][6], acc[i][7]);
            *(float4*)&ft[(size_t)node * NHD + tx * 8]     = s0;
            *(float4*)&ft[(size_t)node * NHD + tx * 8 + 4] = s1;
        }
        float pl = 0.f, pr = 0.f;
#pragma unroll
        for (int j = 0; j < 8; ++j) {
            pl = fmaf(acc[i][j], al[j], pl);
            pr = fmaf(acc[i][j], ar[j], pr);
        }
        // reduce over the 4 threads (tx&3) covering one head
        pl += __shfl_xor(pl, 1); pl += __shfl_xor(pl, 2);
        pr += __shfl_xor(pr, 1); pr += __shfl_xor(pr, 2);
        if ((tx & 3) == 0 && node < N_NODES) {
            a1[node * HEADS + (tx >> 2)] = pl;
            a2[node * HEADS + (tx >> 2)] = pr;
        }
    }
}

// ---------------------------------------------------------------- hist ----
__global__ void hist_kernel(const int* __restrict__ dst, int* __restrict__ deg) {
    int i = blockIdx.x * blockDim.x + threadIdx.x;
    if (i < N_EDGES) atomicAdd(&deg[dst[i]], 1);
}

// ---------------------------------------------------------------- scan ----
// exclusive prefix sum of deg -> offsets[N+1]; single block of 1024.
__global__ void scan_kernel(const int* __restrict__ deg, int* __restrict__ offsets) {
    __shared__ int wsum[16];
    __shared__ int s_carry;
    const int tid  = threadIdx.x;
    const int lane = tid & 63;
    const int wid  = tid >> 6;
    if (tid == 0) s_carry = 0;
    __syncthreads();
    for (int base = 0; base < N_NODES; base += 1024) {
        int i = base + tid;
        int v = (i < N_NODES) ? deg[i] : 0;
        int x = v;
#pragma unroll
        for (int o = 1; o < 64; o <<= 1) {
            int y = __shfl_up(x, o);
            if (lane >= o) x += y;
        }
        if (lane == 63) wsum[wid] = x;
        __syncthreads();
        if (tid == 0) {
            int run = s_carry;
#pragma unroll
            for (int w2 = 0; w2 < 16; ++w2) { int t2 = wsum[w2]; wsum[w2] = run; run += t2; }
            s_carry = run;
        }
        __syncthreads();
        if (i < N_NODES) offsets[i] = wsum[wid] + x - v;
        __syncthreads();
    }
    if (tid == 0) offsets[N_NODES] = s_carry;
}

// ---------------------------------------------------------------- fill ----
__global__ void fill_kernel(const int* __restrict__ src, const int* __restrict__ dst,
                            const int* __restrict__ offsets, int* __restrict__ cursor,
                            int* __restrict__ src_sorted) {
    int i = blockIdx.x * blockDim.x + threadIdx.x;
    if (i < N_EDGES) {
        int d   = dst[i];
        int pos = atomicAdd(&cursor[d], 1);
        src_sorted[offsets[d] + pos] = src[i];
    }
}

// ----------------------------------------------------------------- agg ----
// One wave per dst node. lane l covers out dims [2l, 2l+1]; head h = l>>4.
// Single pass: accumulate w*ft[src] and w; divide at the end (softmax denom inline,
// max-subtraction skipped: |e| <~ 4 so exp cannot overflow; mathematically identical).
// Software-pipelined: next edge's src index + a1 gather issued before current FMA.
__launch_bounds__(256)
__global__ void agg_kernel(const float* __restrict__ ft,
                           const float* __restrict__ a1,
                           const float* __restrict__ a2,
                           const int* __restrict__ offsets,
                           const int* __restrict__ src_sorted,
                           float* __restrict__ out) {
    const int wave = threadIdx.x >> 6;
    const int lane = threadIdx.x & 63;
    const int node = blockIdx.x * 4 + wave;
    if (node >= N_NODES) return;
    const int h = lane >> 4;

    const float a2v = a2[node * HEADS + h];
    const int e0 = offsets[node];
    const int e1 = offsets[node + 1];

    float accx = 0.f, accy = 0.f, wsum = 0.f;

    if (e1 > e0) {
        // pipeline stage: current edge's (s, a1v) already in flight
        int   s   = src_sorted[e0];
        float a1v = a1[s * HEADS + h];
        for (int e = e0; e < e1; ++e) {
            // issue next edge's loads before consuming current
            int   s_nx = 0;
            float a1_nx = 0.f;
            if (e + 1 < e1) {
                s_nx  = src_sorted[e + 1];
                a1_nx = a1[s_nx * HEADS + h];
            }
            float ev = a1v + a2v;
            ev       = ev > 0.f ? ev : LEAKY * ev;
            float w  = __expf(ev);
            float2 v = *(const float2*)&ft[(size_t)s * NHD + lane * 2];
            accx = fmaf(w, v.x, accx);
            accy = fmaf(w, v.y, accy);
            wsum += w;
            s   = s_nx;
            a1v = a1_nx;
        }
    }
    float inv = (e1 > e0) ? 1.f / wsum : 0.f;
    float2 o = make_float2(accx * inv, accy * inv);
    *(float2*)&out[(size_t)node * NHD + lane * 2] = o;
}

// -------------------------------------------------------------- launch ----
extern "C" void kernel_launch(void* const* d_in, const int* in_sizes, int n_in,
                              void* d_out, int out_size, void* d_ws, size_t ws_size,
                              hipStream_t stream) {
    const float* feature = (const float*)d_in[0];
    const int*   src     = (const int*)d_in[1];
    const int*   dst     = (const int*)d_in[2];
    const float* W       = (const float*)d_in[3];
    const float* attn_l  = (const float*)d_in[4];
    const float* attn_r  = (const float*)d_in[5];
    float*       out     = (float*)d_out;

    char* ws = (char*)d_ws;
    size_t off = 0;
    auto alloc = [&](size_t bytes) -> void* {
        void* p = ws + off;
        off = (off + bytes + 255) & ~(size_t)255;
        return p;
    };
    float* ft         = (float*)alloc((size_t)N_NODES * NHD * 4);
    float* a1         = (float*)alloc((size_t)N_NODES * HEADS * 4);
    float* a2         = (float*)alloc((size_t)N_NODES * HEADS * 4);
    int*   deg        = (int*)alloc((size_t)N_NODES * 4);
    int*   cursor     = (int*)alloc((size_t)N_NODES * 4);
    int*   offsets    = (int*)alloc((size_t)(N_NODES + 1) * 4);
    int*   src_sorted = (int*)alloc((size_t)N_EDGES * 4);

    init_kernel<<<(N_NODES + 255) / 256, 256, 0, stream>>>(deg, cursor);
    gemm_kernel<<<(N_NODES + 63) / 64, 256, 0, stream>>>(feature, W, attn_l, attn_r, ft, a1, a2);
    hist_kernel<<<(N_EDGES + 255) / 256, 256, 0, stream>>>(dst, deg);
    scan_kernel<<<1, 1024, 0, stream>>>(deg, offsets);
    fill_kernel<<<(N_EDGES + 255) / 256, 256, 0, stream>>>(src, dst, offsets, cursor, src_sorted);
    agg_kernel<<<(N_NODES + 3) / 4, 256, 0, stream>>>(ft, a1, a2, offsets, src_sorted, out);
}

// Round 5
// 552.836 us; speedup vs baseline: 1.1696x; 1.1696x over previous
//
#include <hip/hip_runtime.h>

#define N_NODES 100000
#define N_EDGES 1600000
#define IN_DIM 256
#define HEADS 4
#define OUT_DIM 32
#define NHD 128          // HEADS*OUT_DIM
#define LEAKY 0.2f

#define SCAN_BLOCK 1024
#define N_SCAN_BLOCKS ((N_NODES + SCAN_BLOCK - 1) / SCAN_BLOCK)   // 98

// ---------------------------------------------------------------- init ----
__global__ void init_kernel(int* __restrict__ deg) {
    int i = blockIdx.x * blockDim.x + threadIdx.x;
    if (i < N_NODES) deg[i] = 0;
}

// ---------------------------------------------------------------- gemm ----
// ft[N,128] = feature[N,256] @ W[256,128]; fused a1/a2 = sum(ft*attn_{l,r}, -1).
// 128 nodes x 128 cols per block, K-tiles of 32; per thread 8x8 register tile:
// per k-step 4x ds_read_b128 -> 64 FMA (vs 12 LDS ops -> 32 FMA before).
__launch_bounds__(256, 2)
__global__ void gemm_kernel(const float* __restrict__ feature,
                            const float* __restrict__ W,
                            const float* __restrict__ attn_l,
                            const float* __restrict__ attn_r,
                            float* __restrict__ ft,
                            float* __restrict__ a1,
                            float* __restrict__ a2) {
    __shared__ float sA[32][132];   // transposed [k][node], 16.9 KB
    __shared__ float sW[32][132];   // [k][col],             16.9 KB
    const int t  = threadIdx.x;
    const int tx = t & 15;          // col group: cols tx*8 .. tx*8+7 (head tx>>2)
    const int ty = t >> 4;          // node group: nodes ty*8 .. ty*8+7
    const int nb = blockIdx.x * 128;

    float acc[8][8];
#pragma unroll
    for (int i = 0; i < 8; ++i)
#pragma unroll
        for (int j = 0; j < 8; ++j) acc[i][j] = 0.f;

    for (int kt = 0; kt < 8; ++kt) {
        __syncthreads();
        // feature tile: 128 nodes x 32 k, stored transposed [k][node]
#pragma unroll
        for (int p = 0; p < 4; ++p) {
            int idx  = t + p * 256;       // 0..1023 float4 slots
            int row  = idx >> 3;          // node 0..127
            int c4   = idx & 7;           // float4 index within 32 k
            int node = nb + row;
            float4 v = make_float4(0.f, 0.f, 0.f, 0.f);
            if (node < N_NODES)
                v = *(const float4*)&feature[(size_t)node * IN_DIM + kt * 32 + c4 * 4];
            sA[c4 * 4 + 0][row] = v.x;
            sA[c4 * 4 + 1][row] = v.y;
            sA[c4 * 4 + 2][row] = v.z;
            sA[c4 * 4 + 3][row] = v.w;
        }
        // W tile: 32 k x 128 cols
#pragma unroll
        for (int p = 0; p < 4; ++p) {
            int idx = t + p * 256;        // 0..1023 float4 slots
            int row = idx >> 5;           // k 0..31
            int c4  = idx & 31;           // float4 col
            float4 v = *(const float4*)&W[(size_t)(kt * 32 + row) * NHD + c4 * 4];
            *(float4*)&sW[row][c4 * 4] = v;
        }
        __syncthreads();

#pragma unroll 8
        for (int k = 0; k < 32; ++k) {
            float4 a0 = *(const float4*)&sA[k][ty * 8];
            float4 a1v = *(const float4*)&sA[k][ty * 8 + 4];
            float4 b0 = *(const float4*)&sW[k][tx * 8];
            float4 b1 = *(const float4*)&sW[k][tx * 8 + 4];
            float a[8] = {a0.x, a0.y, a0.z, a0.w, a1v.x, a1v.y, a1v.z, a1v.w};
            float b[8] = {b0.x, b0.y, b0.z, b0.w, b1.x, b1.y, b1.z, b1.w};
#pragma unroll
            for (int i = 0; i < 8; ++i)
#pragma unroll
                for (int j = 0; j < 8; ++j)
                    acc[i][j] = fmaf(a[i], b[j], acc[i][j]);
        }
    }

    // attn vectors for my 8 cols (all within one head: head = tx>>2)
    float al[8], ar[8];
#pragma unroll
    for (int j = 0; j < 8; ++j) {
        al[j] = attn_l[tx * 8 + j];
        ar[j] = attn_r[tx * 8 + j];
    }

#pragma unroll
    for (int i = 0; i < 8; ++i) {
        int node = nb + ty * 8 + i;
        if (node < N_NODES) {
            float4 s0 = make_float4(acc[i][0], acc[i][1], acc[i][2], acc[i][3]);
            float4 s1 = make_float4(acc[i][4], acc[i][5], acc[i][6], acc[i][7]);
            *(float4*)&ft[(size_t)node * NHD + tx * 8]     = s0;
            *(float4*)&ft[(size_t)node * NHD + tx * 8 + 4] = s1;
        }
        float pl = 0.f, pr = 0.f;
#pragma unroll
        for (int j = 0; j < 8; ++j) {
            pl = fmaf(acc[i][j], al[j], pl);
            pr = fmaf(acc[i][j], ar[j], pr);
        }
        // reduce over the 4 threads (tx&3) covering one head; stays in-wave
        pl += __shfl_xor(pl, 1); pl += __shfl_xor(pl, 2);
        pr += __shfl_xor(pr, 1); pr += __shfl_xor(pr, 2);
        if ((tx & 3) == 0 && node < N_NODES) {
            a1[node * HEADS + (tx >> 2)] = pl;
            a2[node * HEADS + (tx >> 2)] = pr;
        }
    }
}

// ---------------------------------------------------------------- hist ----
__global__ void hist_kernel(const int* __restrict__ dst, int* __restrict__ deg) {
    int i = blockIdx.x * blockDim.x + threadIdx.x;
    if (i < N_EDGES) atomicAdd(&deg[dst[i]], 1);
}

// ------------------------------------------------------ hierarchical scan --
// scan1: per-block (1024 elems) exclusive scan -> partial[i], blocksum[b]
__global__ void scan1_kernel(const int* __restrict__ deg,
                             int* __restrict__ partial,
                             int* __restrict__ blocksum) {
    __shared__ int wsum[16];
    const int tid  = threadIdx.x;
    const int lane = tid & 63;
    const int wid  = tid >> 6;
    const int i    = blockIdx.x * SCAN_BLOCK + tid;
    int v = (i < N_NODES) ? deg[i] : 0;
    int x = v;
#pragma unroll
    for (int o = 1; o < 64; o <<= 1) {
        int y = __shfl_up(x, o);
        if (lane >= o) x += y;
    }
    if (lane == 63) wsum[wid] = x;
    __syncthreads();
    if (wid == 0 && lane < 16) {
        int w = wsum[lane];
#pragma unroll
        for (int o = 1; o < 16; o <<= 1) {
            int y = __shfl_up(w, o);
            if (lane >= o) w += y;
        }
        wsum[lane] = w;   // inclusive scan of wave sums
    }
    __syncthreads();
    int woff = (wid > 0) ? wsum[wid - 1] : 0;
    if (i < N_NODES) partial[i] = woff + x - v;
    if (tid == SCAN_BLOCK - 1) blocksum[blockIdx.x] = wsum[15];
}

// scan2: single small block scans the 98 block sums; writes offsets[N] = total
__global__ void scan2_kernel(const int* __restrict__ blocksum,
                             int* __restrict__ blockoff,
                             int* __restrict__ offsets) {
    __shared__ int wtot[2];
    const int tid  = threadIdx.x;     // 128 threads
    const int lane = tid & 63;
    const int wid  = tid >> 6;
    int v = (tid < N_SCAN_BLOCKS) ? blocksum[tid] : 0;
    int x = v;
#pragma unroll
    for (int o = 1; o < 64; o <<= 1) {
        int y = __shfl_up(x, o);
        if (lane >= o) x += y;
    }
    if (lane == 63) wtot[wid] = x;
    __syncthreads();
    int add = (wid == 1) ? wtot[0] : 0;
    if (tid < N_SCAN_BLOCKS) blockoff[tid] = add + x - v;
    if (tid == N_SCAN_BLOCKS - 1) offsets[N_NODES] = add + x;
}

// scan3: offsets[i] = cursor[i] = partial[i] + blockoff[block]
__global__ void scan3_kernel(const int* __restrict__ partial,
                             const int* __restrict__ blockoff,
                             int* __restrict__ offsets,
                             int* __restrict__ cursor) {
    int i = blockIdx.x * SCAN_BLOCK + threadIdx.x;
    if (i < N_NODES) {
        int v = partial[i] + blockoff[blockIdx.x];
        offsets[i] = v;
        cursor[i]  = v;
    }
}

// ---------------------------------------------------------------- fill ----
// cursor holds absolute base per segment -> atomicAdd gives final slot directly
__global__ void fill_kernel(const int* __restrict__ src, const int* __restrict__ dst,
                            int* __restrict__ cursor, int* __restrict__ src_sorted) {
    int i = blockIdx.x * blockDim.x + threadIdx.x;
    if (i < N_EDGES) {
        int idx = atomicAdd(&cursor[dst[i]], 1);
        src_sorted[idx] = src[i];
    }
}

// ----------------------------------------------------------------- agg ----
// One wave per dst node. lane l covers out dims [2l, 2l+1]; head h = l>>4.
// Softmax denom accumulated inline (max-subtraction skipped: |e|<~4, no overflow).
// Unrolled x4: four independent src->a1/ft load chains in flight per lane.
__launch_bounds__(256)
__global__ void agg_kernel(const float* __restrict__ ft,
                           const float* __restrict__ a1,
                           const float* __restrict__ a2,
                           const int* __restrict__ offsets,
                           const int* __restrict__ src_sorted,
                           float* __restrict__ out) {
    const int wave = threadIdx.x >> 6;
    const int lane = threadIdx.x & 63;
    const int node = blockIdx.x * 4 + wave;
    if (node >= N_NODES) return;
    const int h = lane >> 4;

    const float a2v = a2[node * HEADS + h];
    const int e0 = offsets[node];
    const int e1 = offsets[node + 1];

    float accx = 0.f, accy = 0.f, wsum = 0.f;
    int e = e0;

    for (; e + 3 < e1; e += 4) {
        int s0 = src_sorted[e];
        int s1 = src_sorted[e + 1];
        int s2 = src_sorted[e + 2];
        int s3 = src_sorted[e + 3];
        float b0 = a1[s0 * HEADS + h];
        float b1 = a1[s1 * HEADS + h];
        float b2 = a1[s2 * HEADS + h];
        float b3 = a1[s3 * HEADS + h];
        float2 v0 = *(const float2*)&ft[(size_t)s0 * NHD + lane * 2];
        float2 v1 = *(const float2*)&ft[(size_t)s1 * NHD + lane * 2];
        float2 v2 = *(const float2*)&ft[(size_t)s2 * NHD + lane * 2];
        float2 v3 = *(const float2*)&ft[(size_t)s3 * NHD + lane * 2];
        float ev0 = b0 + a2v; ev0 = ev0 > 0.f ? ev0 : LEAKY * ev0;
        float ev1 = b1 + a2v; ev1 = ev1 > 0.f ? ev1 : LEAKY * ev1;
        float ev2 = b2 + a2v; ev2 = ev2 > 0.f ? ev2 : LEAKY * ev2;
        float ev3 = b3 + a2v; ev3 = ev3 > 0.f ? ev3 : LEAKY * ev3;
        float w0 = __expf(ev0), w1 = __expf(ev1), w2 = __expf(ev2), w3 = __expf(ev3);
        accx = fmaf(w0, v0.x, accx); accy = fmaf(w0, v0.y, accy);
        accx = fmaf(w1, v1.x, accx); accy = fmaf(w1, v1.y, accy);
        accx = fmaf(w2, v2.x, accx); accy = fmaf(w2, v2.y, accy);
        accx = fmaf(w3, v3.x, accx); accy = fmaf(w3, v3.y, accy);
        wsum += w0 + w1 + w2 + w3;
    }
    for (; e < e1; ++e) {
        int s    = src_sorted[e];
        float ev = a1[s * HEADS + h] + a2v;
        ev       = ev > 0.f ? ev : LEAKY * ev;
        float w  = __expf(ev);
        float2 v = *(const float2*)&ft[(size_t)s * NHD + lane * 2];
        accx = fmaf(w, v.x, accx);
        accy = fmaf(w, v.y, accy);
        wsum += w;
    }
    float inv = (e1 > e0) ? 1.f / wsum : 0.f;
    float2 o = make_float2(accx * inv, accy * inv);
    *(float2*)&out[(size_t)node * NHD + lane * 2] = o;
}

// -------------------------------------------------------------- launch ----
extern "C" void kernel_launch(void* const* d_in, const int* in_sizes, int n_in,
                              void* d_out, int out_size, void* d_ws, size_t ws_size,
                              hipStream_t stream) {
    const float* feature = (const float*)d_in[0];
    const int*   src     = (const int*)d_in[1];
    const int*   dst     = (const int*)d_in[2];
    const float* W       = (const float*)d_in[3];
    const float* attn_l  = (const float*)d_in[4];
    const float* attn_r  = (const float*)d_in[5];
    float*       out     = (float*)d_out;

    char* ws = (char*)d_ws;
    size_t off = 0;
    auto alloc = [&](size_t bytes) -> void* {
        void* p = ws + off;
        off = (off + bytes + 255) & ~(size_t)255;
        return p;
    };
    float* ft         = (float*)alloc((size_t)N_NODES * NHD * 4);
    float* a1         = (float*)alloc((size_t)N_NODES * HEADS * 4);
    float* a2         = (float*)alloc((size_t)N_NODES * HEADS * 4);
    int*   deg        = (int*)alloc((size_t)N_NODES * 4);
    int*   cursor     = (int*)alloc((size_t)N_NODES * 4);
    int*   offsets    = (int*)alloc((size_t)(N_NODES + 1) * 4);
    int*   src_sorted = (int*)alloc((size_t)N_EDGES * 4);
    int*   partial    = (int*)alloc((size_t)N_NODES * 4);
    int*   blocksum   = (int*)alloc((size_t)N_SCAN_BLOCKS * 4);
    int*   blockoff   = (int*)alloc((size_t)N_SCAN_BLOCKS * 4);

    init_kernel<<<(N_NODES + 255) / 256, 256, 0, stream>>>(deg);
    gemm_kernel<<<(N_NODES + 127) / 128, 256, 0, stream>>>(feature, W, attn_l, attn_r, ft, a1, a2);
    hist_kernel<<<(N_EDGES + 255) / 256, 256, 0, stream>>>(dst, deg);
    scan1_kernel<<<N_SCAN_BLOCKS, SCAN_BLOCK, 0, stream>>>(deg, partial, blocksum);
    scan2_kernel<<<1, 128, 0, stream>>>(blocksum, blockoff, offsets);
    scan3_kernel<<<N_SCAN_BLOCKS, SCAN_BLOCK, 0, stream>>>(partial, blockoff, offsets, cursor);
    fill_kernel<<<(N_EDGES + 255) / 256, 256, 0, stream>>>(src, dst, cursor, src_sorted);
    agg_kernel<<<(N_NODES + 3) / 4, 256, 0, stream>>>(ft, a1, a2, offsets, src_sorted, out);
}

// Round 6
// 427.855 us; speedup vs baseline: 1.5112x; 1.2921x over previous
//
#include <hip/hip_runtime.h>
#include <hip/hip_fp16.h>

#define N_NODES 100000
#define N_EDGES 1600000
#define IN_DIM 256
#define HEADS 4
#define OUT_DIM 32
#define NHD 128          // HEADS*OUT_DIM
#define LEAKY 0.2f

#define SCAN_BLOCK 1024
#define N_SCAN_BLOCKS ((N_NODES + SCAN_BLOCK - 1) / SCAN_BLOCK)   // 98

// ---------------------------------------------------------------- init ----
__global__ void init_kernel(int* __restrict__ deg) {
    int i = blockIdx.x * blockDim.x + threadIdx.x;
    if (i < N_NODES) deg[i] = 0;
}

// ---------------------------------------------------------------- gemm ----
// ft[N,128] (fp16) = feature[N,256] @ W[256,128]; fused a1/a2 (fp32) per head.
// 128 nodes x 128 cols per block, K-tiles of 32; per thread 8x8 register tile.
__launch_bounds__(256, 2)
__global__ void gemm_kernel(const float* __restrict__ feature,
                            const float* __restrict__ W,
                            const float* __restrict__ attn_l,
                            const float* __restrict__ attn_r,
                            __half* __restrict__ ft,
                            float* __restrict__ a1,
                            float* __restrict__ a2) {
    __shared__ float sA[32][132];   // transposed [k][node], 16.9 KB
    __shared__ float sW[32][132];   // [k][col],             16.9 KB
    const int t  = threadIdx.x;
    const int tx = t & 15;          // col group: cols tx*8 .. tx*8+7 (head tx>>2)
    const int ty = t >> 4;          // node group: nodes ty*8 .. ty*8+7
    const int nb = blockIdx.x * 128;

    float acc[8][8];
#pragma unroll
    for (int i = 0; i < 8; ++i)
#pragma unroll
        for (int j = 0; j < 8; ++j) acc[i][j] = 0.f;

    for (int kt = 0; kt < 8; ++kt) {
        __syncthreads();
        // feature tile: 128 nodes x 32 k, stored transposed [k][node]
#pragma unroll
        for (int p = 0; p < 4; ++p) {
            int idx  = t + p * 256;       // 0..1023 float4 slots
            int row  = idx >> 3;          // node 0..127
            int c4   = idx & 7;           // float4 index within 32 k
            int node = nb + row;
            float4 v = make_float4(0.f, 0.f, 0.f, 0.f);
            if (node < N_NODES)
                v = *(const float4*)&feature[(size_t)node * IN_DIM + kt * 32 + c4 * 4];
            sA[c4 * 4 + 0][row] = v.x;
            sA[c4 * 4 + 1][row] = v.y;
            sA[c4 * 4 + 2][row] = v.z;
            sA[c4 * 4 + 3][row] = v.w;
        }
        // W tile: 32 k x 128 cols
#pragma unroll
        for (int p = 0; p < 4; ++p) {
            int idx = t + p * 256;        // 0..1023 float4 slots
            int row = idx >> 5;           // k 0..31
            int c4  = idx & 31;           // float4 col
            float4 v = *(const float4*)&W[(size_t)(kt * 32 + row) * NHD + c4 * 4];
            *(float4*)&sW[row][c4 * 4] = v;
        }
        __syncthreads();

#pragma unroll 8
        for (int k = 0; k < 32; ++k) {
            float4 a0  = *(const float4*)&sA[k][ty * 8];
            float4 a1v = *(const float4*)&sA[k][ty * 8 + 4];
            float4 b0  = *(const float4*)&sW[k][tx * 8];
            float4 b1  = *(const float4*)&sW[k][tx * 8 + 4];
            float a[8] = {a0.x, a0.y, a0.z, a0.w, a1v.x, a1v.y, a1v.z, a1v.w};
            float b[8] = {b0.x, b0.y, b0.z, b0.w, b1.x, b1.y, b1.z, b1.w};
#pragma unroll
            for (int i = 0; i < 8; ++i)
#pragma unroll
                for (int j = 0; j < 8; ++j)
                    acc[i][j] = fmaf(a[i], b[j], acc[i][j]);
        }
    }

    // attn vectors for my 8 cols (all within one head: head = tx>>2)
    float al[8], ar[8];
#pragma unroll
    for (int j = 0; j < 8; ++j) {
        al[j] = attn_l[tx * 8 + j];
        ar[j] = attn_r[tx * 8 + j];
    }

#pragma unroll
    for (int i = 0; i < 8; ++i) {
        int node = nb + ty * 8 + i;
        if (node < N_NODES) {
            // convert 8 fp32 -> 8 fp16, one 16B store
            __half2 pack[4];
            pack[0] = __floats2half2_rn(acc[i][0], acc[i][1]);
            pack[1] = __floats2half2_rn(acc[i][2], acc[i][3]);
            pack[2] = __floats2half2_rn(acc[i][4], acc[i][5]);
            pack[3] = __floats2half2_rn(acc[i][6], acc[i][7]);
            *(float4*)&ft[(size_t)node * NHD + tx * 8] = *(float4*)pack;
        }
        float pl = 0.f, pr = 0.f;
#pragma unroll
        for (int j = 0; j < 8; ++j) {
            pl = fmaf(acc[i][j], al[j], pl);
            pr = fmaf(acc[i][j], ar[j], pr);
        }
        // reduce over the 4 threads (tx&3) covering one head; stays in-wave
        pl += __shfl_xor(pl, 1); pl += __shfl_xor(pl, 2);
        pr += __shfl_xor(pr, 1); pr += __shfl_xor(pr, 2);
        if ((tx & 3) == 0 && node < N_NODES) {
            a1[node * HEADS + (tx >> 2)] = pl;
            a2[node * HEADS + (tx >> 2)] = pr;
        }
    }
}

// ---------------------------------------------------------------- hist ----
// also records each edge's rank within its dst segment (coalesced write) so
// fill needs no atomics.
__global__ void hist_kernel(const int* __restrict__ dst, int* __restrict__ deg,
                            int* __restrict__ edge_pos) {
    int i = blockIdx.x * blockDim.x + threadIdx.x;
    if (i < N_EDGES) edge_pos[i] = atomicAdd(&deg[dst[i]], 1);
}

// ------------------------------------------------------ hierarchical scan --
__global__ void scan1_kernel(const int* __restrict__ deg,
                             int* __restrict__ partial,
                             int* __restrict__ blocksum) {
    __shared__ int wsum[16];
    const int tid  = threadIdx.x;
    const int lane = tid & 63;
    const int wid  = tid >> 6;
    const int i    = blockIdx.x * SCAN_BLOCK + tid;
    int v = (i < N_NODES) ? deg[i] : 0;
    int x = v;
#pragma unroll
    for (int o = 1; o < 64; o <<= 1) {
        int y = __shfl_up(x, o);
        if (lane >= o) x += y;
    }
    if (lane == 63) wsum[wid] = x;
    __syncthreads();
    if (wid == 0 && lane < 16) {
        int w = wsum[lane];
#pragma unroll
        for (int o = 1; o < 16; o <<= 1) {
            int y = __shfl_up(w, o);
            if (lane >= o) w += y;
        }
        wsum[lane] = w;   // inclusive scan of wave sums
    }
    __syncthreads();
    int woff = (wid > 0) ? wsum[wid - 1] : 0;
    if (i < N_NODES) partial[i] = woff + x - v;
    if (tid == SCAN_BLOCK - 1) blocksum[blockIdx.x] = wsum[15];
}

__global__ void scan2_kernel(const int* __restrict__ blocksum,
                             int* __restrict__ blockoff,
                             int* __restrict__ offsets) {
    __shared__ int wtot[2];
    const int tid  = threadIdx.x;     // 128 threads
    const int lane = tid & 63;
    const int wid  = tid >> 6;
    int v = (tid < N_SCAN_BLOCKS) ? blocksum[tid] : 0;
    int x = v;
#pragma unroll
    for (int o = 1; o < 64; o <<= 1) {
        int y = __shfl_up(x, o);
        if (lane >= o) x += y;
    }
    if (lane == 63) wtot[wid] = x;
    __syncthreads();
    int add = (wid == 1) ? wtot[0] : 0;
    if (tid < N_SCAN_BLOCKS) blockoff[tid] = add + x - v;
    if (tid == N_SCAN_BLOCKS - 1) offsets[N_NODES] = add + x;
}

__global__ void scan3_kernel(const int* __restrict__ partial,
                             const int* __restrict__ blockoff,
                             int* __restrict__ offsets) {
    int i = blockIdx.x * SCAN_BLOCK + threadIdx.x;
    if (i < N_NODES) offsets[i] = partial[i] + blockoff[blockIdx.x];
}

// ---------------------------------------------------------------- fill ----
// atomic-free scatter: slot = offsets[dst] + edge_pos (precomputed in hist)
__global__ void fill_kernel(const int* __restrict__ src, const int* __restrict__ dst,
                            const int* __restrict__ offsets,
                            const int* __restrict__ edge_pos,
                            int* __restrict__ src_sorted) {
    int i = blockIdx.x * blockDim.x + threadIdx.x;
    if (i < N_EDGES) {
        int idx = offsets[dst[i]] + edge_pos[i];
        src_sorted[idx] = src[i];
    }
}

// ----------------------------------------------------------------- agg ----
// One wave per dst node. lane l covers out dims [2l, 2l+1]; head h = l>>4.
// ft gathered as fp16 (half the bytes of fp32), accumulated in fp32.
// Softmax denom accumulated inline (max-subtraction skipped: |e|<~4, no overflow).
// Unrolled x4: four independent src->a1/ft load chains in flight per lane.
__launch_bounds__(256)
__global__ void agg_kernel(const __half* __restrict__ ft,
                           const float* __restrict__ a1,
                           const float* __restrict__ a2,
                           const int* __restrict__ offsets,
                           const int* __restrict__ src_sorted,
                           float* __restrict__ out) {
    const int wave = threadIdx.x >> 6;
    const int lane = threadIdx.x & 63;
    const int node = blockIdx.x * 4 + wave;
    if (node >= N_NODES) return;
    const int h = lane >> 4;

    const float a2v = a2[node * HEADS + h];
    const int e0 = offsets[node];
    const int e1 = offsets[node + 1];

    float accx = 0.f, accy = 0.f, wsum = 0.f;
    int e = e0;

    for (; e + 3 < e1; e += 4) {
        int s0 = src_sorted[e];
        int s1 = src_sorted[e + 1];
        int s2 = src_sorted[e + 2];
        int s3 = src_sorted[e + 3];
        float b0 = a1[s0 * HEADS + h];
        float b1 = a1[s1 * HEADS + h];
        float b2 = a1[s2 * HEADS + h];
        float b3 = a1[s3 * HEADS + h];
        __half2 h0 = *(const __half2*)&ft[(size_t)s0 * NHD + lane * 2];
        __half2 h1 = *(const __half2*)&ft[(size_t)s1 * NHD + lane * 2];
        __half2 h2 = *(const __half2*)&ft[(size_t)s2 * NHD + lane * 2];
        __half2 h3 = *(const __half2*)&ft[(size_t)s3 * NHD + lane * 2];
        float2 v0 = __half22float2(h0);
        float2 v1 = __half22float2(h1);
        float2 v2 = __half22float2(h2);
        float2 v3 = __half22float2(h3);
        float ev0 = b0 + a2v; ev0 = ev0 > 0.f ? ev0 : LEAKY * ev0;
        float ev1 = b1 + a2v; ev1 = ev1 > 0.f ? ev1 : LEAKY * ev1;
        float ev2 = b2 + a2v; ev2 = ev2 > 0.f ? ev2 : LEAKY * ev2;
        float ev3 = b3 + a2v; ev3 = ev3 > 0.f ? ev3 : LEAKY * ev3;
        float w0 = __expf(ev0), w1 = __expf(ev1), w2 = __expf(ev2), w3 = __expf(ev3);
        accx = fmaf(w0, v0.x, accx); accy = fmaf(w0, v0.y, accy);
        accx = fmaf(w1, v1.x, accx); accy = fmaf(w1, v1.y, accy);
        accx = fmaf(w2, v2.x, accx); accy = fmaf(w2, v2.y, accy);
        accx = fmaf(w3, v3.x, accx); accy = fmaf(w3, v3.y, accy);
        wsum += w0 + w1 + w2 + w3;
    }
    for (; e < e1; ++e) {
        int s    = src_sorted[e];
        float ev = a1[s * HEADS + h] + a2v;
        ev       = ev > 0.f ? ev : LEAKY * ev;
        float w  = __expf(ev);
        float2 v = __half22float2(*(const __half2*)&ft[(size_t)s * NHD + lane * 2]);
        accx = fmaf(w, v.x, accx);
        accy = fmaf(w, v.y, accy);
        wsum += w;
    }
    float inv = (e1 > e0) ? 1.f / wsum : 0.f;
    float2 o = make_float2(accx * inv, accy * inv);
    *(float2*)&out[(size_t)node * NHD + lane * 2] = o;
}

// -------------------------------------------------------------- launch ----
extern "C" void kernel_launch(void* const* d_in, const int* in_sizes, int n_in,
                              void* d_out, int out_size, void* d_ws, size_t ws_size,
                              hipStream_t stream) {
    const float* feature = (const float*)d_in[0];
    const int*   src     = (const int*)d_in[1];
    const int*   dst     = (const int*)d_in[2];
    const float* W       = (const float*)d_in[3];
    const float* attn_l  = (const float*)d_in[4];
    const float* attn_r  = (const float*)d_in[5];
    float*       out     = (float*)d_out;

    char* ws = (char*)d_ws;
    size_t off = 0;
    auto alloc = [&](size_t bytes) -> void* {
        void* p = ws + off;
        off = (off + bytes + 255) & ~(size_t)255;
        return p;
    };
    __half* ft        = (__half*)alloc((size_t)N_NODES * NHD * 2);
    float* a1         = (float*)alloc((size_t)N_NODES * HEADS * 4);
    float* a2         = (float*)alloc((size_t)N_NODES * HEADS * 4);
    int*   deg        = (int*)alloc((size_t)N_NODES * 4);
    int*   offsets    = (int*)alloc((size_t)(N_NODES + 1) * 4);
    int*   src_sorted = (int*)alloc((size_t)N_EDGES * 4);
    int*   edge_pos   = (int*)alloc((size_t)N_EDGES * 4);
    int*   partial    = (int*)alloc((size_t)N_NODES * 4);
    int*   blocksum   = (int*)alloc((size_t)N_SCAN_BLOCKS * 4);
    int*   blockoff   = (int*)alloc((size_t)N_SCAN_BLOCKS * 4);

    init_kernel<<<(N_NODES + 255) / 256, 256, 0, stream>>>(deg);
    gemm_kernel<<<(N_NODES + 127) / 128, 256, 0, stream>>>(feature, W, attn_l, attn_r, ft, a1, a2);
    hist_kernel<<<(N_EDGES + 255) / 256, 256, 0, stream>>>(dst, deg, edge_pos);
    scan1_kernel<<<N_SCAN_BLOCKS, SCAN_BLOCK, 0, stream>>>(deg, partial, blocksum);
    scan2_kernel<<<1, 128, 0, stream>>>(blocksum, blockoff, offsets);
    scan3_kernel<<<N_SCAN_BLOCKS, SCAN_BLOCK, 0, stream>>>(partial, blockoff, offsets);
    fill_kernel<<<(N_EDGES + 255) / 256, 256, 0, stream>>>(src, dst, offsets, edge_pos, src_sorted);
    agg_kernel<<<(N_NODES + 3) / 4, 256, 0, stream>>>(ft, a1, a2, offsets, src_sorted, out);
}

// Round 7
// 391.579 us; speedup vs baseline: 1.6512x; 1.0926x over previous
//
#include <hip/hip_runtime.h>
#include <hip/hip_fp16.h>

#define N_NODES 100000
#define N_EDGES 1600000
#define IN_DIM 256
#define HEADS 4
#define OUT_DIM 32
#define NHD 128          // HEADS*OUT_DIM
#define LEAKY 0.2f

#define SCAN_BLOCK 1024
#define N_SCAN_BLOCKS ((N_NODES + SCAN_BLOCK - 1) / SCAN_BLOCK)   // 98

typedef _Float16 f16x8 __attribute__((ext_vector_type(8)));
typedef _Float16 f16x4 __attribute__((ext_vector_type(4)));
typedef float    f32x4 __attribute__((ext_vector_type(4)));

// ---------------------------------------------------------------- init ----
__global__ void init_kernel(int* __restrict__ deg) {
    int i = blockIdx.x * blockDim.x + threadIdx.x;
    if (i < N_NODES) deg[i] = 0;
}

// ---------------------------------------------------------------- wprep ----
// Wt_hi/Wt_lo [128 cols][256 k] fp16, transposed from W[256][128] fp32.
// W = hi + lo exactly to ~2e-7 rel -> split-W MFMA gives fp32-grade weights.
__global__ void wprep_kernel(const float* __restrict__ W,
                             _Float16* __restrict__ Wt_hi,
                             _Float16* __restrict__ Wt_lo) {
    int i = blockIdx.x * blockDim.x + threadIdx.x;   // 32768
    if (i < NHD * IN_DIM) {
        int c = i >> 8;          // col 0..127
        int k = i & 255;         // k   0..255
        float w = W[(size_t)k * NHD + c];
        _Float16 hi = (_Float16)w;
        _Float16 lo = (_Float16)(w - (float)hi);
        Wt_hi[i] = hi;
        Wt_lo[i] = lo;
    }
}

// ---------------------------------------------------------------- gemm ----
// ft[N,128](fp16) = feature @ W via mfma_f32_16x16x32_f16, split-W for accuracy.
// Block: 128 nodes x 128 cols, 4 waves; wave w owns cols [w*32, w*32+32) = head w.
// Swapped operands: D = mfma(Wt_frag, feat_frag) -> lane&15 = node,
// (lane>>4)*4+r = col -> 4 consecutive cols per acc reg -> packed stores,
// and per-head a1/a2 reduce is shfl_xor(16)+shfl_xor(32).
__launch_bounds__(256, 4)
__global__ void gemm_kernel(const float* __restrict__ feature,
                            const _Float16* __restrict__ Wt_hi,
                            const _Float16* __restrict__ Wt_lo,
                            const float* __restrict__ attn_l,
                            const float* __restrict__ attn_r,
                            __half* __restrict__ ft,
                            float* __restrict__ a1,
                            float* __restrict__ a2) {
    // stride 40 halves = 80 B: 16B-aligned b128 rows, 2-way banks (free)
    __shared__ _Float16 sA [128][40];   // feature tile [node][k]  10 KB
    __shared__ _Float16 sWh[128][40];   // Wt_hi tile  [col][k]    10 KB
    __shared__ _Float16 sWl[128][40];   // Wt_lo tile  [col][k]    10 KB

    const int t    = threadIdx.x;
    const int w    = t >> 6;        // wave = head
    const int lane = t & 63;
    const int l15  = lane & 15;
    const int kg   = lane >> 4;     // k-group 0..3
    const int nb   = blockIdx.x * 128;

    f32x4 acc[8][2];
#pragma unroll
    for (int nt = 0; nt < 8; ++nt) {
        acc[nt][0] = (f32x4){0.f, 0.f, 0.f, 0.f};
        acc[nt][1] = (f32x4){0.f, 0.f, 0.f, 0.f};
    }

    for (int kt = 0; kt < 8; ++kt) {
        __syncthreads();
        // stage feature 128 nodes x 32 k -> fp16
#pragma unroll
        for (int p = 0; p < 4; ++p) {
            int idx  = t + p * 256;       // 0..1023 float4 slots
            int node = idx >> 3;          // 0..127
            int c4   = idx & 7;           // float4 within 32 k
            float4 v = make_float4(0.f, 0.f, 0.f, 0.f);
            if (nb + node < N_NODES)
                v = *(const float4*)&feature[(size_t)(nb + node) * IN_DIM + kt * 32 + c4 * 4];
            f16x4 h;
            h[0] = (_Float16)v.x; h[1] = (_Float16)v.y;
            h[2] = (_Float16)v.z; h[3] = (_Float16)v.w;
            *(f16x4*)&sA[node][c4 * 4] = h;
        }
        // stage Wt_hi / Wt_lo: 128 cols x 32 k (fp16 copy, L2-hot)
#pragma unroll
        for (int p = 0; p < 2; ++p) {
            int c   = t + p * 256;        // 0..511 chunks of 8 halves
            int col = c >> 2;
            int kc  = c & 3;
            *(f16x8*)&sWh[col][kc * 8] =
                *(const f16x8*)&Wt_hi[(size_t)col * IN_DIM + kt * 32 + kc * 8];
            *(f16x8*)&sWl[col][kc * 8] =
                *(const f16x8*)&Wt_lo[(size_t)col * IN_DIM + kt * 32 + kc * 8];
        }
        __syncthreads();

        // W frags for my wave's 2 col-tiles
        f16x8 wh0 = *(const f16x8*)&sWh[w * 32 + l15][kg * 8];
        f16x8 wh1 = *(const f16x8*)&sWh[w * 32 + 16 + l15][kg * 8];
        f16x8 wl0 = *(const f16x8*)&sWl[w * 32 + l15][kg * 8];
        f16x8 wl1 = *(const f16x8*)&sWl[w * 32 + 16 + l15][kg * 8];

#pragma unroll
        for (int nt = 0; nt < 8; ++nt) {
            f16x8 af = *(const f16x8*)&sA[nt * 16 + l15][kg * 8];
            acc[nt][0] = __builtin_amdgcn_mfma_f32_16x16x32_f16(wh0, af, acc[nt][0], 0, 0, 0);
            acc[nt][0] = __builtin_amdgcn_mfma_f32_16x16x32_f16(wl0, af, acc[nt][0], 0, 0, 0);
            acc[nt][1] = __builtin_amdgcn_mfma_f32_16x16x32_f16(wh1, af, acc[nt][1], 0, 0, 0);
            acc[nt][1] = __builtin_amdgcn_mfma_f32_16x16x32_f16(wl1, af, acc[nt][1], 0, 0, 0);
        }
    }

    // attn coefficients for my 8 (ct,r) columns (head = w)
    float al8[8], ar8[8];
#pragma unroll
    for (int ct = 0; ct < 2; ++ct)
#pragma unroll
        for (int r = 0; r < 4; ++r) {
            int cb = ct * 16 + kg * 4 + r;
            al8[ct * 4 + r] = attn_l[w * 32 + cb];
            ar8[ct * 4 + r] = attn_r[w * 32 + cb];
        }

#pragma unroll
    for (int nt = 0; nt < 8; ++nt) {
        int node = nb + nt * 16 + l15;
        bool valid = node < N_NODES;
        if (valid) {
            f16x4 s0, s1;
#pragma unroll
            for (int r = 0; r < 4; ++r) {
                s0[r] = (_Float16)acc[nt][0][r];
                s1[r] = (_Float16)acc[nt][1][r];
            }
            *(f16x4*)&ft[(size_t)node * NHD + w * 32 + kg * 4]      = s0;
            *(f16x4*)&ft[(size_t)node * NHD + w * 32 + 16 + kg * 4] = s1;
        }
        float pl = 0.f, pr = 0.f;
#pragma unroll
        for (int ct = 0; ct < 2; ++ct)
#pragma unroll
            for (int r = 0; r < 4; ++r) {
                pl = fmaf(acc[nt][ct][r], al8[ct * 4 + r], pl);
                pr = fmaf(acc[nt][ct][r], ar8[ct * 4 + r], pr);
            }
        pl += __shfl_xor(pl, 16); pl += __shfl_xor(pl, 32);
        pr += __shfl_xor(pr, 16); pr += __shfl_xor(pr, 32);
        if (kg == 0 && valid) {
            a1[node * HEADS + w] = pl;
            a2[node * HEADS + w] = pr;
        }
    }
}

// ---------------------------------------------------------------- hist ----
__global__ void hist_kernel(const int* __restrict__ dst, int* __restrict__ deg,
                            int* __restrict__ edge_pos) {
    int i = blockIdx.x * blockDim.x + threadIdx.x;
    if (i < N_EDGES) edge_pos[i] = atomicAdd(&deg[dst[i]], 1);
}

// ------------------------------------------------------ hierarchical scan --
__global__ void scan1_kernel(const int* __restrict__ deg,
                             int* __restrict__ partial,
                             int* __restrict__ blocksum) {
    __shared__ int wsum[16];
    const int tid  = threadIdx.x;
    const int lane = tid & 63;
    const int wid  = tid >> 6;
    const int i    = blockIdx.x * SCAN_BLOCK + tid;
    int v = (i < N_NODES) ? deg[i] : 0;
    int x = v;
#pragma unroll
    for (int o = 1; o < 64; o <<= 1) {
        int y = __shfl_up(x, o);
        if (lane >= o) x += y;
    }
    if (lane == 63) wsum[wid] = x;
    __syncthreads();
    if (wid == 0 && lane < 16) {
        int w = wsum[lane];
#pragma unroll
        for (int o = 1; o < 16; o <<= 1) {
            int y = __shfl_up(w, o);
            if (lane >= o) w += y;
        }
        wsum[lane] = w;
    }
    __syncthreads();
    int woff = (wid > 0) ? wsum[wid - 1] : 0;
    if (i < N_NODES) partial[i] = woff + x - v;
    if (tid == SCAN_BLOCK - 1) blocksum[blockIdx.x] = wsum[15];
}

__global__ void scan2_kernel(const int* __restrict__ blocksum,
                             int* __restrict__ blockoff,
                             int* __restrict__ offsets) {
    __shared__ int wtot[2];
    const int tid  = threadIdx.x;     // 128 threads
    const int lane = tid & 63;
    const int wid  = tid >> 6;
    int v = (tid < N_SCAN_BLOCKS) ? blocksum[tid] : 0;
    int x = v;
#pragma unroll
    for (int o = 1; o < 64; o <<= 1) {
        int y = __shfl_up(x, o);
        if (lane >= o) x += y;
    }
    if (lane == 63) wtot[wid] = x;
    __syncthreads();
    int add = (wid == 1) ? wtot[0] : 0;
    if (tid < N_SCAN_BLOCKS) blockoff[tid] = add + x - v;
    if (tid == N_SCAN_BLOCKS - 1) offsets[N_NODES] = add + x;
}

__global__ void scan3_kernel(const int* __restrict__ partial,
                             const int* __restrict__ blockoff,
                             int* __restrict__ offsets) {
    int i = blockIdx.x * SCAN_BLOCK + threadIdx.x;
    if (i < N_NODES) offsets[i] = partial[i] + blockoff[blockIdx.x];
}

// ---------------------------------------------------------------- fill ----
__global__ void fill_kernel(const int* __restrict__ src, const int* __restrict__ dst,
                            const int* __restrict__ offsets,
                            const int* __restrict__ edge_pos,
                            int* __restrict__ src_sorted) {
    int i = blockIdx.x * blockDim.x + threadIdx.x;
    if (i < N_EDGES) {
        int idx = offsets[dst[i]] + edge_pos[i];
        src_sorted[idx] = src[i];
    }
}

// ----------------------------------------------------------------- agg ----
__launch_bounds__(256)
__global__ void agg_kernel(const __half* __restrict__ ft,
                           const float* __restrict__ a1,
                           const float* __restrict__ a2,
                           const int* __restrict__ offsets,
                           const int* __restrict__ src_sorted,
                           float* __restrict__ out) {
    const int wave = threadIdx.x >> 6;
    const int lane = threadIdx.x & 63;
    const int node = blockIdx.x * 4 + wave;
    if (node >= N_NODES) return;
    const int h = lane >> 4;

    const float a2v = a2[node * HEADS + h];
    const int e0 = offsets[node];
    const int e1 = offsets[node + 1];

    float accx = 0.f, accy = 0.f, wsum = 0.f;
    int e = e0;

    for (; e + 3 < e1; e += 4) {
        int s0 = src_sorted[e];
        int s1 = src_sorted[e + 1];
        int s2 = src_sorted[e + 2];
        int s3 = src_sorted[e + 3];
        float b0 = a1[s0 * HEADS + h];
        float b1 = a1[s1 * HEADS + h];
        float b2 = a1[s2 * HEADS + h];
        float b3 = a1[s3 * HEADS + h];
        __half2 h0 = *(const __half2*)&ft[(size_t)s0 * NHD + lane * 2];
        __half2 h1 = *(const __half2*)&ft[(size_t)s1 * NHD + lane * 2];
        __half2 h2 = *(const __half2*)&ft[(size_t)s2 * NHD + lane * 2];
        __half2 h3 = *(const __half2*)&ft[(size_t)s3 * NHD + lane * 2];
        float2 v0 = __half22float2(h0);
        float2 v1 = __half22float2(h1);
        float2 v2 = __half22float2(h2);
        float2 v3 = __half22float2(h3);
        float ev0 = b0 + a2v; ev0 = ev0 > 0.f ? ev0 : LEAKY * ev0;
        float ev1 = b1 + a2v; ev1 = ev1 > 0.f ? ev1 : LEAKY * ev1;
        float ev2 = b2 + a2v; ev2 = ev2 > 0.f ? ev2 : LEAKY * ev2;
        float ev3 = b3 + a2v; ev3 = ev3 > 0.f ? ev3 : LEAKY * ev3;
        float w0 = __expf(ev0), w1 = __expf(ev1), w2 = __expf(ev2), w3 = __expf(ev3);
        accx = fmaf(w0, v0.x, accx); accy = fmaf(w0, v0.y, accy);
        accx = fmaf(w1, v1.x, accx); accy = fmaf(w1, v1.y, accy);
        accx = fmaf(w2, v2.x, accx); accy = fmaf(w2, v2.y, accy);
        accx = fmaf(w3, v3.x, accx); accy = fmaf(w3, v3.y, accy);
        wsum += w0 + w1 + w2 + w3;
    }
    for (; e < e1; ++e) {
        int s    = src_sorted[e];
        float ev = a1[s * HEADS + h] + a2v;
        ev       = ev > 0.f ? ev : LEAKY * ev;
        float w  = __expf(ev);
        float2 v = __half22float2(*(const __half2*)&ft[(size_t)s * NHD + lane * 2]);
        accx = fmaf(w, v.x, accx);
        accy = fmaf(w, v.y, accy);
        wsum += w;
    }
    float inv = (e1 > e0) ? 1.f / wsum : 0.f;
    float2 o = make_float2(accx * inv, accy * inv);
    *(float2*)&out[(size_t)node * NHD + lane * 2] = o;
}

// -------------------------------------------------------------- launch ----
extern "C" void kernel_launch(void* const* d_in, const int* in_sizes, int n_in,
                              void* d_out, int out_size, void* d_ws, size_t ws_size,
                              hipStream_t stream) {
    const float* feature = (const float*)d_in[0];
    const int*   src     = (const int*)d_in[1];
    const int*   dst     = (const int*)d_in[2];
    const float* W       = (const float*)d_in[3];
    const float* attn_l  = (const float*)d_in[4];
    const float* attn_r  = (const float*)d_in[5];
    float*       out     = (float*)d_out;

    char* ws = (char*)d_ws;
    size_t off = 0;
    auto alloc = [&](size_t bytes) -> void* {
        void* p = ws + off;
        off = (off + bytes + 255) & ~(size_t)255;
        return p;
    };
    __half*    ft        = (__half*)alloc((size_t)N_NODES * NHD * 2);
    float*     a1        = (float*)alloc((size_t)N_NODES * HEADS * 4);
    float*     a2        = (float*)alloc((size_t)N_NODES * HEADS * 4);
    int*       deg       = (int*)alloc((size_t)N_NODES * 4);
    int*       offsets   = (int*)alloc((size_t)(N_NODES + 1) * 4);
    int*       src_sorted= (int*)alloc((size_t)N_EDGES * 4);
    int*       edge_pos  = (int*)alloc((size_t)N_EDGES * 4);
    int*       partial   = (int*)alloc((size_t)N_NODES * 4);
    int*       blocksum  = (int*)alloc((size_t)N_SCAN_BLOCKS * 4);
    int*       blockoff  = (int*)alloc((size_t)N_SCAN_BLOCKS * 4);
    _Float16*  Wt_hi     = (_Float16*)alloc((size_t)NHD * IN_DIM * 2);
    _Float16*  Wt_lo     = (_Float16*)alloc((size_t)NHD * IN_DIM * 2);

    init_kernel<<<(N_NODES + 255) / 256, 256, 0, stream>>>(deg);
    wprep_kernel<<<(NHD * IN_DIM + 255) / 256, 256, 0, stream>>>(W, Wt_hi, Wt_lo);
    gemm_kernel<<<(N_NODES + 127) / 128, 256, 0, stream>>>(feature, Wt_hi, Wt_lo,
                                                           attn_l, attn_r, ft, a1, a2);
    hist_kernel<<<(N_EDGES + 255) / 256, 256, 0, stream>>>(dst, deg, edge_pos);
    scan1_kernel<<<N_SCAN_BLOCKS, SCAN_BLOCK, 0, stream>>>(deg, partial, blocksum);
    scan2_kernel<<<1, 128, 0, stream>>>(blocksum, blockoff, offsets);
    scan3_kernel<<<N_SCAN_BLOCKS, SCAN_BLOCK, 0, stream>>>(partial, blockoff, offsets);
    fill_kernel<<<(N_EDGES + 255) / 256, 256, 0, stream>>>(src, dst, offsets, edge_pos, src_sorted);
    agg_kernel<<<(N_NODES + 3) / 4, 256, 0, stream>>>(ft, a1, a2, offsets, src_sorted, out);
}